// Round 8
// baseline (159.239 us; speedup 1.0000x reference)
//
#include <hip/hip_runtime.h>
#include <hip/hip_bf16.h>

#define N_RAW  100000
#define DIM    256
#define OUTD   128
#define KN     10
#define N1N    40960
#define BATCH  4096

#define SNP    6252   // ceil(100000/16) 16-row strips
#define NBP    256    // gemm_P grid (1 block/CU at 8 waves)
#define SNQ    2560   // 40960/16
#define NBQ    512

typedef __attribute__((ext_vector_type(8))) short bf16x8;
typedef __attribute__((ext_vector_type(4))) float f32x4;
typedef __attribute__((ext_vector_type(4))) unsigned int u32x4;
typedef unsigned int u32;

static __device__ inline float b2f(short s) {
  unsigned u = ((unsigned)(unsigned short)s) << 16;
  return __builtin_bit_cast(float, u);
}
static __device__ inline short f2b(float f) {
  unsigned u = __builtin_bit_cast(unsigned, f);
  unsigned r = (u + 0x7fff + ((u >> 16) & 1)) >> 16;  // RNE
  return (short)r;
}
static __device__ inline u32 cvtpk(float lo, float hi) {
  u32 r;
  asm("v_cvt_pk_bf16_f32 %0, %1, %2" : "=v"(r) : "v"(lo), "v"(hi));
  return r;  // [15:0]=bf16(lo), [31:16]=bf16(hi)
}

// ---- combined weights, bf16, plain row-major ----
// W1c[256][256]: row j<128 -> W1[j][0:256], j>=128 -> W1[j-128][256:512]
// W2c[256][128]: row j<128 -> W2[j][0:128], j>=128 -> W2[j-128][128:256]
__global__ void build_wc(const float* __restrict__ W1, const float* __restrict__ W2,
                         short* __restrict__ W1c, short* __restrict__ W2c) {
  int i = blockIdx.x * blockDim.x + threadIdx.x;   // 65536 total
  {
    int j = i >> 8, k = i & 255;
    float v = (j < OUTD) ? W1[j * (2 * DIM) + k] : W1[(j - OUTD) * (2 * DIM) + DIM + k];
    W1c[j * 256 + k] = f2b(v);
  }
  if (i < 256 * 128) {
    int j = i >> 7, k = i & 127;
    float v = (j < OUTD) ? W2[j * (2 * OUTD) + k] : W2[(j - OUTD) * (2 * OUTD) + OUTD + k];
    W2c[j * 128 + k] = f2b(v);
  }
}

// ---- P[100000,256] = raw[100000,256]_f32 @ W1c^T (bf16 out) ----
// Barrier-free streaming: 8 waves/block, wave owns 32 cols; B[2][8]=64 VGPR
// register-stationary (amdgpu_waves_per_eu(2,2) removes the allocator's
// occupancy incentive to rematerialize B). Grid-stride over 16-row strips,
// next strip's 16 dwordx4 A-loads issued before the MFMAs of the current.
// mfma_f32_16x16x32_bf16 frags (m89/m91): A row=lane&15 k=(lane>>4)*8+e;
// B col=lane&15 same k; D col=lane&15 row=(lane>>4)*4+e.
__global__ __launch_bounds__(512) __attribute__((amdgpu_waves_per_eu(2, 2)))
void gemm_P(const float* __restrict__ raw, const short* __restrict__ W1c,
            short* __restrict__ P) {
  const int tid  = threadIdx.x;
  const int wave = tid >> 6, lane = tid & 63;
  const int r16  = lane & 15, kg = lane >> 4;
  const int col0 = wave * 32;

  // B-slice: cols col0 + n*16 + r16, k = ks*32 + kg*8 .. +8 (one-time)
  bf16x8 B[2][8];
#pragma unroll
  for (int n = 0; n < 2; ++n)
#pragma unroll
    for (int ks = 0; ks < 8; ++ks)
      B[n][ks] = *(const bf16x8*)(W1c + (size_t)(col0 + n * 16 + r16) * 256 + ks * 32 + kg * 8);

  int s = blockIdx.x;
  float4 af[16];
  {
    int r = s * 16 + r16; if (r > N_RAW - 1) r = N_RAW - 1;
    const float* x = raw + (size_t)r * DIM + kg * 8;
#pragma unroll
    for (int ks = 0; ks < 8; ++ks) {
      af[2 * ks]     = *(const float4*)(x + ks * 32);
      af[2 * ks + 1] = *(const float4*)(x + ks * 32 + 4);
    }
  }

  for (; s < SNP; s += NBP) {
    // convert current strip (waits its loads; issued an iteration ago)
    bf16x8 ab[8];
#pragma unroll
    for (int ks = 0; ks < 8; ++ks) {
      float4 lo = af[2 * ks], hi = af[2 * ks + 1];
      u32x4 t;
      t.x = cvtpk(lo.x, lo.y); t.y = cvtpk(lo.z, lo.w);
      t.z = cvtpk(hi.x, hi.y); t.w = cvtpk(hi.z, hi.w);
      ab[ks] = __builtin_bit_cast(bf16x8, t);
    }
    // issue next strip's loads (hide HBM latency under MFMA + stores)
    {
      int sn = s + NBP; if (sn >= SNP) sn = s;
      int r = sn * 16 + r16; if (r > N_RAW - 1) r = N_RAW - 1;
      const float* x = raw + (size_t)r * DIM + kg * 8;
#pragma unroll
      for (int ks = 0; ks < 8; ++ks) {
        af[2 * ks]     = *(const float4*)(x + ks * 32);
        af[2 * ks + 1] = *(const float4*)(x + ks * 32 + 4);
      }
    }

    f32x4 acc[2];
    acc[0] = (f32x4){0.f, 0.f, 0.f, 0.f};
    acc[1] = (f32x4){0.f, 0.f, 0.f, 0.f};
#pragma unroll
    for (int ks = 0; ks < 8; ++ks) {
      acc[0] = __builtin_amdgcn_mfma_f32_16x16x32_bf16(ab[ks], B[0][ks], acc[0], 0, 0, 0);
      acc[1] = __builtin_amdgcn_mfma_f32_16x16x32_bf16(ab[ks], B[1][ks], acc[1], 0, 0, 0);
    }

    int rbase = s * 16 + kg * 4;
#pragma unroll
    for (int n = 0; n < 2; ++n)
#pragma unroll
      for (int j = 0; j < 4; ++j) {
        int r = rbase + j;
        if (r < N_RAW) P[(size_t)r * 256 + (col0 + n * 16 + r16)] = f2b(acc[n][j]);
      }
  }
}

// ---- Q[40960,256] = h1[40960,128]_bf16 @ W2c^T (bf16 out), same template ----
__global__ __launch_bounds__(512)
void gemm_Q(const short* __restrict__ h1, const short* __restrict__ W2c,
            short* __restrict__ Q) {
  const int tid  = threadIdx.x;
  const int wave = tid >> 6, lane = tid & 63;
  const int r16  = lane & 15, kg = lane >> 4;
  const int col0 = wave * 32;

  bf16x8 B[2][4];
#pragma unroll
  for (int n = 0; n < 2; ++n)
#pragma unroll
    for (int ks = 0; ks < 4; ++ks)
      B[n][ks] = *(const bf16x8*)(W2c + (size_t)(col0 + n * 16 + r16) * 128 + ks * 32 + kg * 8);

  int s = blockIdx.x;
  bf16x8 a[4];
  {
    const short* x = h1 + (size_t)(s * 16 + r16) * OUTD + kg * 8;
#pragma unroll
    for (int ks = 0; ks < 4; ++ks) a[ks] = *(const bf16x8*)(x + ks * 32);
  }

  for (; s < SNQ; s += NBQ) {
    bf16x8 an[4];
    {
      int sn = s + NBQ; if (sn >= SNQ) sn = s;
      const short* x = h1 + (size_t)(sn * 16 + r16) * OUTD + kg * 8;
#pragma unroll
      for (int ks = 0; ks < 4; ++ks) an[ks] = *(const bf16x8*)(x + ks * 32);
    }

    f32x4 acc[2];
    acc[0] = (f32x4){0.f, 0.f, 0.f, 0.f};
    acc[1] = (f32x4){0.f, 0.f, 0.f, 0.f};
#pragma unroll
    for (int ks = 0; ks < 4; ++ks) {
      acc[0] = __builtin_amdgcn_mfma_f32_16x16x32_bf16(a[ks], B[0][ks], acc[0], 0, 0, 0);
      acc[1] = __builtin_amdgcn_mfma_f32_16x16x32_bf16(a[ks], B[1][ks], acc[1], 0, 0, 0);
    }

    int rbase = s * 16 + kg * 4;
#pragma unroll
    for (int n = 0; n < 2; ++n)
#pragma unroll
      for (int j = 0; j < 4; ++j)
        Q[(size_t)(rbase + j) * 256 + (col0 + n * 16 + r16)] = f2b(acc[n][j]);

#pragma unroll
    for (int ks = 0; ks < 4; ++ks) a[ks] = an[ks];
  }
}

// ---- h1[i] = relu(P[nodes1[i]][0:128] + 0.1 * sum_k P[neighs1[i,k]][128:256]) ----
__global__ void gather1(const short* __restrict__ P, const int* __restrict__ nodes1,
                        const int* __restrict__ neighs1, short* __restrict__ h1) {
  int g = threadIdx.x >> 4, t = threadIdx.x & 15;
  int row = blockIdx.x * 16 + g;
  int sn = nodes1[row];
  bf16x8 sv = *(const bf16x8*)(P + (size_t)sn * 256 + t * 8);
  float acc[8];
#pragma unroll
  for (int e = 0; e < 8; ++e) acc[e] = 0.f;
#pragma unroll
  for (int k = 0; k < KN; ++k) {
    int nn = neighs1[row * KN + k];
    bf16x8 nv = *(const bf16x8*)(P + (size_t)nn * 256 + 128 + t * 8);
#pragma unroll
    for (int e = 0; e < 8; ++e) acc[e] += b2f(nv[e]);
  }
  bf16x8 o;
#pragma unroll
  for (int e = 0; e < 8; ++e) o[e] = f2b(fmaxf(b2f(sv[e]) + 0.1f * acc[e], 0.f));
  *(bf16x8*)(h1 + (size_t)row * OUTD + t * 8) = o;
}

// ---- out[i] = relu(Q[map2[i]][0:128] + 0.1 * sum_k Q[neighs2[i,k]][128:256]) f32 ----
__global__ void gather2(const short* __restrict__ Q, const int* __restrict__ map2,
                        const int* __restrict__ neighs2, float* __restrict__ out) {
  int g = threadIdx.x >> 4, t = threadIdx.x & 15;
  int row = blockIdx.x * 16 + g;
  int sn = map2[row];
  bf16x8 sv = *(const bf16x8*)(Q + (size_t)sn * 256 + t * 8);
  float acc[8];
#pragma unroll
  for (int e = 0; e < 8; ++e) acc[e] = 0.f;
#pragma unroll
  for (int k = 0; k < KN; ++k) {
    int nn = neighs2[row * KN + k];
    bf16x8 nv = *(const bf16x8*)(Q + (size_t)nn * 256 + 128 + t * 8);
#pragma unroll
    for (int e = 0; e < 8; ++e) acc[e] += b2f(nv[e]);
  }
  float* orow = out + (size_t)row * OUTD + t * 8;
  float4 o0, o1;
  o0.x = fmaxf(b2f(sv[0]) + 0.1f * acc[0], 0.f);
  o0.y = fmaxf(b2f(sv[1]) + 0.1f * acc[1], 0.f);
  o0.z = fmaxf(b2f(sv[2]) + 0.1f * acc[2], 0.f);
  o0.w = fmaxf(b2f(sv[3]) + 0.1f * acc[3], 0.f);
  o1.x = fmaxf(b2f(sv[4]) + 0.1f * acc[4], 0.f);
  o1.y = fmaxf(b2f(sv[5]) + 0.1f * acc[5], 0.f);
  o1.z = fmaxf(b2f(sv[6]) + 0.1f * acc[6], 0.f);
  o1.w = fmaxf(b2f(sv[7]) + 0.1f * acc[7], 0.f);
  *(float4*)orow = o0;
  *(float4*)(orow + 4) = o1;
}

extern "C" void kernel_launch(void* const* d_in, const int* in_sizes, int n_in,
                              void* d_out, int out_size, void* d_ws, size_t ws_size,
                              hipStream_t stream) {
  const float* raw     = (const float*)d_in[0];
  const float* W1      = (const float*)d_in[1];
  const float* W2      = (const float*)d_in[2];
  const int*   nodes1  = (const int*)d_in[3];
  const int*   neighs1 = (const int*)d_in[4];
  const int*   map2    = (const int*)d_in[5];
  const int*   neighs2 = (const int*)d_in[6];
  float* out = (float*)d_out;

  char* ws = (char*)d_ws;
  short* W1c = (short*)(ws);                 // 131,072 B
  short* W2c = (short*)(ws + 131072);        //  65,536 B
  short* P   = (short*)(ws + 196608);        // 100000*256*2 = 51,200,000 B
  short* Q   = (short*)(ws + 196608);        // alias (P dead after gather1)
  short* h1  = (short*)(ws + 51396608);      // 40960*128*2 = 10,485,760 B
                                             // total 61,882,368 B

  build_wc<<<256, 256, 0, stream>>>(W1, W2, W1c, W2c);
  gemm_P<<<NBP, 512, 0, stream>>>(raw, W1c, P);
  gather1<<<N1N / 16, 256, 0, stream>>>(P, nodes1, neighs1, h1);
  gemm_Q<<<NBQ, 512, 0, stream>>>(h1, W2c, Q);
  gather2<<<BATCH / 16, 256, 0, stream>>>(Q, map2, neighs2, out);
}

// Round 9
// 152.555 us; speedup vs baseline: 1.0438x; 1.0438x over previous
//
#include <hip/hip_runtime.h>
#include <hip/hip_bf16.h>

#define N_RAW  100000
#define DIM    256
#define OUTD   128
#define KN     10
#define N1N    40960
#define BATCH  4096

#define SNP    6252   // ceil(100000/16) 16-row strips
#define NBP    256    // gemm_P grid: 1 block/CU, 16 waves each, 2 strips in flight
#define SNQ    2560   // 40960/16
#define NBQ    512

typedef __attribute__((ext_vector_type(8))) short bf16x8;
typedef __attribute__((ext_vector_type(4))) float f32x4;
typedef __attribute__((ext_vector_type(4))) unsigned int u32x4;
typedef unsigned int u32;

static __device__ inline float b2f(short s) {
  unsigned u = ((unsigned)(unsigned short)s) << 16;
  return __builtin_bit_cast(float, u);
}
static __device__ inline short f2b(float f) {
  unsigned u = __builtin_bit_cast(unsigned, f);
  unsigned r = (u + 0x7fff + ((u >> 16) & 1)) >> 16;  // RNE
  return (short)r;
}
static __device__ inline u32 cvtpk(float lo, float hi) {
  u32 r;
  asm("v_cvt_pk_bf16_f32 %0, %1, %2" : "=v"(r) : "v"(lo), "v"(hi));
  return r;  // [15:0]=bf16(lo), [31:16]=bf16(hi)
}
static __device__ inline void gload_lds16(const void* g, void* l) {
  __builtin_amdgcn_global_load_lds((const __attribute__((address_space(1))) u32*)g,
                                   (__attribute__((address_space(3))) u32*)l, 16, 0, 0);
}

// ---- combined weights, bf16, pre-swizzled full images ----
// W1c image: j in [0,256) combined rows, k in [0,256): byte = j*512 + ((2k)^((j&7)<<4))
// W2c image: j in [0,256), k in [0,128):              byte = j*256 + ((2k)^((j&7)<<4))
__global__ void build_wc(const float* __restrict__ W1, const float* __restrict__ W2,
                         short* __restrict__ W1c, short* __restrict__ W2c) {
  int i = blockIdx.x * blockDim.x + threadIdx.x;   // 65536 total
  {
    int j = i >> 8, k = i & 255;
    float v = (j < OUTD) ? W1[j * (2 * DIM) + k] : W1[(j - OUTD) * (2 * DIM) + DIM + k];
    u32 byte = (u32)(j * 512) + (((u32)(k * 2)) ^ ((u32)(j & 7) << 4));
    *(short*)((char*)W1c + byte) = f2b(v);
  }
  if (i < 256 * 128) {
    int j = i >> 7, k = i & 127;
    float v = (j < OUTD) ? W2[j * (2 * OUTD) + k] : W2[(j - OUTD) * (2 * OUTD) + OUTD + k];
    u32 byte = (u32)(j * 256) + (((u32)(k * 2)) ^ ((u32)(j & 7) << 4));
    *(short*)((char*)W2c + byte) = f2b(v);
  }
}

// ---- P[100000,256] = raw[100000,256]_f32 @ W1c^T (bf16 out) ----
// B fully LDS-resident (128 KB, staged once, ONE barrier total). 16 waves;
// wave group h=wave>>3 streams its own 16-row strip; wave owns 32 cols.
// Steady state: zero barriers, ds_read_b128 B-frags (cheap, latency-hidden),
// next strip's 16 dwordx4 A-loads issued before current MFMAs.
// mfma_f32_16x16x32_bf16 frags (m89/m91): A row=lane&15 k=(lane>>4)*8+e;
// B col=lane&15 same k; D col=lane&15 row=(lane>>4)*4+e.
__global__ __launch_bounds__(1024)
void gemm_P(const float* __restrict__ raw, const short* __restrict__ W1c,
            short* __restrict__ P) {
  __shared__ char Blds[131072];
  const int tid  = threadIdx.x;
  const int wave = tid >> 6, lane = tid & 63;
  const int r16  = lane & 15, kg = lane >> 4;
  const int col0 = (wave & 7) * 32;
  const int harm = wave >> 3;
  const u32 swz  = (u32)(r16 & 7) << 4;

  // stage whole W1c image: 8 iters x (1024 thr x 16 B) = 128 KB, linear
#pragma unroll
  for (int it = 0; it < 8; ++it)
    gload_lds16((const char*)W1c + it * 16384 + wave * 1024 + lane * 16,
                Blds + it * 16384 + wave * 1024);

  // B-frag LDS byte offsets (row j = col0 + n*16 + r16; j&7 == r16&7)
  const u32 jb0 = (u32)((col0 + r16) * 512);
  const u32 jb1 = (u32)((col0 + 16 + r16) * 512);
  const u32 koff = (u32)(kg * 16);

  int s = blockIdx.x + harm * NBP;   // residues cover [0, 2*NBP)
  float4 af[16];
  {
    int r = s * 16 + r16; if (r > N_RAW - 1) r = N_RAW - 1;
    const float* x = raw + (size_t)r * DIM + kg * 8;
#pragma unroll
    for (int ks = 0; ks < 8; ++ks) {
      af[2 * ks]     = *(const float4*)(x + ks * 32);
      af[2 * ks + 1] = *(const float4*)(x + ks * 32 + 4);
    }
  }

  __syncthreads();   // LDS staging complete (also drains A loads; one-time)

  for (; s < SNP; s += 2 * NBP) {
    // convert current strip's A (loads issued an iteration ago)
    bf16x8 ab[8];
#pragma unroll
    for (int ks = 0; ks < 8; ++ks) {
      float4 lo = af[2 * ks], hi = af[2 * ks + 1];
      u32x4 t;
      t.x = cvtpk(lo.x, lo.y); t.y = cvtpk(lo.z, lo.w);
      t.z = cvtpk(hi.x, hi.y); t.w = cvtpk(hi.z, hi.w);
      ab[ks] = __builtin_bit_cast(bf16x8, t);
    }
    // issue next strip's A loads (hide HBM latency under ds_read+MFMA)
    {
      int sn = s + 2 * NBP; if (sn >= SNP) sn = s;
      int r = sn * 16 + r16; if (r > N_RAW - 1) r = N_RAW - 1;
      const float* x = raw + (size_t)r * DIM + kg * 8;
#pragma unroll
      for (int ks = 0; ks < 8; ++ks) {
        af[2 * ks]     = *(const float4*)(x + ks * 32);
        af[2 * ks + 1] = *(const float4*)(x + ks * 32 + 4);
      }
    }

    f32x4 acc[2];
    acc[0] = (f32x4){0.f, 0.f, 0.f, 0.f};
    acc[1] = (f32x4){0.f, 0.f, 0.f, 0.f};
#pragma unroll
    for (int ks = 0; ks < 8; ++ks) {
      u32 o = ((u32)(ks * 64) + koff) ^ swz;
      bf16x8 b0 = *(const bf16x8*)(Blds + jb0 + o);
      bf16x8 b1 = *(const bf16x8*)(Blds + jb1 + o);
      acc[0] = __builtin_amdgcn_mfma_f32_16x16x32_bf16(ab[ks], b0, acc[0], 0, 0, 0);
      acc[1] = __builtin_amdgcn_mfma_f32_16x16x32_bf16(ab[ks], b1, acc[1], 0, 0, 0);
    }

    int rbase = s * 16 + kg * 4;
#pragma unroll
    for (int n = 0; n < 2; ++n)
#pragma unroll
      for (int j = 0; j < 4; ++j) {
        int r = rbase + j;
        if (r < N_RAW) P[(size_t)r * 256 + (col0 + n * 16 + r16)] = f2b(acc[n][j]);
      }
  }
}

// ---- Q[40960,256] = h1[40960,128]_bf16 @ W2c^T (bf16 out), same template ----
__global__ __launch_bounds__(512)
void gemm_Q(const short* __restrict__ h1, const short* __restrict__ W2c,
            short* __restrict__ Q) {
  __shared__ char Blds[65536];
  const int tid  = threadIdx.x;
  const int wave = tid >> 6, lane = tid & 63;
  const int r16  = lane & 15, kg = lane >> 4;
  const int col0 = wave * 32;
  const u32 swz  = (u32)(r16 & 7) << 4;

#pragma unroll
  for (int it = 0; it < 8; ++it)
    gload_lds16((const char*)W2c + it * 8192 + wave * 1024 + lane * 16,
                Blds + it * 8192 + wave * 1024);

  const u32 jb0 = (u32)((col0 + r16) * 256);
  const u32 jb1 = (u32)((col0 + 16 + r16) * 256);
  const u32 koff = (u32)(kg * 16);

  int s = blockIdx.x;
  bf16x8 a[4];
  {
    const short* x = h1 + (size_t)(s * 16 + r16) * OUTD + kg * 8;
#pragma unroll
    for (int ks = 0; ks < 4; ++ks) a[ks] = *(const bf16x8*)(x + ks * 32);
  }

  __syncthreads();

  for (; s < SNQ; s += NBQ) {
    bf16x8 an[4];
    {
      int sn = s + NBQ; if (sn >= SNQ) sn = s;
      const short* x = h1 + (size_t)(sn * 16 + r16) * OUTD + kg * 8;
#pragma unroll
      for (int ks = 0; ks < 4; ++ks) an[ks] = *(const bf16x8*)(x + ks * 32);
    }

    f32x4 acc[2];
    acc[0] = (f32x4){0.f, 0.f, 0.f, 0.f};
    acc[1] = (f32x4){0.f, 0.f, 0.f, 0.f};
#pragma unroll
    for (int ks = 0; ks < 4; ++ks) {
      u32 o = ((u32)(ks * 64) + koff) ^ swz;
      bf16x8 b0 = *(const bf16x8*)(Blds + jb0 + o);
      bf16x8 b1 = *(const bf16x8*)(Blds + jb1 + o);
      acc[0] = __builtin_amdgcn_mfma_f32_16x16x32_bf16(a[ks], b0, acc[0], 0, 0, 0);
      acc[1] = __builtin_amdgcn_mfma_f32_16x16x32_bf16(a[ks], b1, acc[1], 0, 0, 0);
    }

    int rbase = s * 16 + kg * 4;
#pragma unroll
    for (int n = 0; n < 2; ++n)
#pragma unroll
      for (int j = 0; j < 4; ++j)
        Q[(size_t)(rbase + j) * 256 + (col0 + n * 16 + r16)] = f2b(acc[n][j]);

#pragma unroll
    for (int ks = 0; ks < 4; ++ks) a[ks] = an[ks];
  }
}

// ---- h1[i] = relu(P[nodes1[i]][0:128] + 0.1 * sum_k P[neighs1[i,k]][128:256]) ----
__global__ void gather1(const short* __restrict__ P, const int* __restrict__ nodes1,
                        const int* __restrict__ neighs1, short* __restrict__ h1) {
  int g = threadIdx.x >> 4, t = threadIdx.x & 15;
  int row = blockIdx.x * 16 + g;
  int sn = nodes1[row];
  bf16x8 sv = *(const bf16x8*)(P + (size_t)sn * 256 + t * 8);
  float acc[8];
#pragma unroll
  for (int e = 0; e < 8; ++e) acc[e] = 0.f;
#pragma unroll
  for (int k = 0; k < KN; ++k) {
    int nn = neighs1[row * KN + k];
    bf16x8 nv = *(const bf16x8*)(P + (size_t)nn * 256 + 128 + t * 8);
#pragma unroll
    for (int e = 0; e < 8; ++e) acc[e] += b2f(nv[e]);
  }
  bf16x8 o;
#pragma unroll
  for (int e = 0; e < 8; ++e) o[e] = f2b(fmaxf(b2f(sv[e]) + 0.1f * acc[e], 0.f));
  *(bf16x8*)(h1 + (size_t)row * OUTD + t * 8) = o;
}

// ---- out[i] = relu(Q[map2[i]][0:128] + 0.1 * sum_k Q[neighs2[i,k]][128:256]) f32 ----
__global__ void gather2(const short* __restrict__ Q, const int* __restrict__ map2,
                        const int* __restrict__ neighs2, float* __restrict__ out) {
  int g = threadIdx.x >> 4, t = threadIdx.x & 15;
  int row = blockIdx.x * 16 + g;
  int sn = map2[row];
  bf16x8 sv = *(const bf16x8*)(Q + (size_t)sn * 256 + t * 8);
  float acc[8];
#pragma unroll
  for (int e = 0; e < 8; ++e) acc[e] = 0.f;
#pragma unroll
  for (int k = 0; k < KN; ++k) {
    int nn = neighs2[row * KN + k];
    bf16x8 nv = *(const bf16x8*)(Q + (size_t)nn * 256 + 128 + t * 8);
#pragma unroll
    for (int e = 0; e < 8; ++e) acc[e] += b2f(nv[e]);
  }
  float* orow = out + (size_t)row * OUTD + t * 8;
  float4 o0, o1;
  o0.x = fmaxf(b2f(sv[0]) + 0.1f * acc[0], 0.f);
  o0.y = fmaxf(b2f(sv[1]) + 0.1f * acc[1], 0.f);
  o0.z = fmaxf(b2f(sv[2]) + 0.1f * acc[2], 0.f);
  o0.w = fmaxf(b2f(sv[3]) + 0.1f * acc[3], 0.f);
  o1.x = fmaxf(b2f(sv[4]) + 0.1f * acc[4], 0.f);
  o1.y = fmaxf(b2f(sv[5]) + 0.1f * acc[5], 0.f);
  o1.z = fmaxf(b2f(sv[6]) + 0.1f * acc[6], 0.f);
  o1.w = fmaxf(b2f(sv[7]) + 0.1f * acc[7], 0.f);
  *(float4*)orow = o0;
  *(float4*)(orow + 4) = o1;
}

extern "C" void kernel_launch(void* const* d_in, const int* in_sizes, int n_in,
                              void* d_out, int out_size, void* d_ws, size_t ws_size,
                              hipStream_t stream) {
  const float* raw     = (const float*)d_in[0];
  const float* W1      = (const float*)d_in[1];
  const float* W2      = (const float*)d_in[2];
  const int*   nodes1  = (const int*)d_in[3];
  const int*   neighs1 = (const int*)d_in[4];
  const int*   map2    = (const int*)d_in[5];
  const int*   neighs2 = (const int*)d_in[6];
  float* out = (float*)d_out;

  char* ws = (char*)d_ws;
  short* W1c = (short*)(ws);                 // 131,072 B (swizzled full image)
  short* W2c = (short*)(ws + 131072);        //  65,536 B (swizzled full image)
  short* P   = (short*)(ws + 196608);        // 100000*256*2 = 51,200,000 B
  short* Q   = (short*)(ws + 196608);        // alias (P dead after gather1)
  short* h1  = (short*)(ws + 51396608);      // 40960*128*2 = 10,485,760 B
                                             // total 61,882,368 B

  build_wc<<<256, 256, 0, stream>>>(W1, W2, W1c, W2c);
  gemm_P<<<NBP, 1024, 0, stream>>>(raw, W1c, P);
  gather1<<<N1N / 16, 256, 0, stream>>>(P, nodes1, neighs1, h1);
  gemm_Q<<<NBQ, 512, 0, stream>>>(h1, W2c, Q);
  gather2<<<BATCH / 16, 256, 0, stream>>>(Q, map2, neighs2, out);
}

// Round 10
// 142.541 us; speedup vs baseline: 1.1171x; 1.0703x over previous
//
#include <hip/hip_runtime.h>
#include <hip/hip_bf16.h>

#define N_RAW  100000
#define DIM    256
#define OUTD   128
#define KN     10
#define N1N    40960
#define BATCH  4096
#define SNP    6250   // 100000/16 exactly
#define SNQ    2560   // 40960/16

typedef __attribute__((ext_vector_type(8))) short bf16x8;
typedef __attribute__((ext_vector_type(4))) float f32x4;
typedef unsigned int u32;

static __device__ inline float b2f(short s) {
  unsigned u = ((unsigned)(unsigned short)s) << 16;
  return __builtin_bit_cast(float, u);
}
static __device__ inline short f2b(float f) {
  unsigned u = __builtin_bit_cast(unsigned, f);
  unsigned r = (u + 0x7fff + ((u >> 16) & 1)) >> 16;  // RNE
  return (short)r;
}
static __device__ inline u32 cvtpk(float lo, float hi) {
  u32 r;
  asm("v_cvt_pk_bf16_f32 %0, %1, %2" : "=v"(r) : "v"(lo), "v"(hi));
  return r;
}
static __device__ inline void gload_lds16(const void* g, void* l) {
  __builtin_amdgcn_global_load_lds((const __attribute__((address_space(1))) u32*)g,
                                   (__attribute__((address_space(3))) u32*)l, 16, 0, 0);
}

// asm-forced vmem/lds ops: cannot be sunk, split, or rematerialized by LLVM
#define GL4(dst, base, OFF) \
  asm volatile("global_load_dwordx4 %0, %1, off offset:" #OFF : "=v"(dst) : "v"(base))
#define GSH(base, val, OFF) \
  asm volatile("global_store_short %0, %1, off offset:" #OFF :: "v"(base), "v"(val) : "memory")
#define DSR(dst, addr) \
  asm volatile("ds_read_b128 %0, %1" : "=v"(dst) : "v"(addr))
#define WAITVM(N)  asm volatile("s_waitcnt vmcnt(" #N ")" ::: "memory")
#define WAITLGKM() asm volatile("s_waitcnt lgkmcnt(0)" ::: "memory")
#define SBAR()     __builtin_amdgcn_sched_barrier(0)

// ---- combined weights, bf16, pre-swizzled half/page images ----
// W1c byte(j,k) = (j>>7)*65536 + (k>>6)*16384 + (j&127)*128 + ((2*(k&63)) ^ ((j&7)<<4))
//   j in [0,256): j<128 -> W1[j][0:256] (self), else W1[j-128][256:512] (agg); k in [0,256)
// W2c byte(j,k) = (j>>7)*32768 + (k>>6)*16384 + (j&127)*128 + ((2*(k&63)) ^ ((j&7)<<4))
//   j in [0,256), k in [0,128)
__global__ void build_wc(const float* __restrict__ W1, const float* __restrict__ W2,
                         short* __restrict__ W1c, short* __restrict__ W2c) {
  int i = blockIdx.x * blockDim.x + threadIdx.x;   // 65536 total
  {
    int j = i >> 8, k = i & 255;
    float v = (j < OUTD) ? W1[j * (2 * DIM) + k] : W1[(j - OUTD) * (2 * DIM) + DIM + k];
    u32 byte = (u32)((j >> 7) * 65536 + (k >> 6) * 16384 + (j & 127) * 128)
             + (((u32)(2 * (k & 63))) ^ ((u32)(j & 7) << 4));
    *(short*)((char*)W1c + byte) = f2b(v);
  }
  if (i < 256 * 128) {
    int j = i >> 7, k = i & 127;
    float v = (j < OUTD) ? W2[j * (2 * OUTD) + k] : W2[(j - OUTD) * (2 * OUTD) + OUTD + k];
    u32 byte = (u32)((j >> 7) * 32768 + (k >> 6) * 16384 + (j & 127) * 128)
             + (((u32)(2 * (k & 63))) ^ ((u32)(j & 7) << 4));
    *(short*)((char*)W2c + byte) = f2b(v);
  }
}

// ---- P[100000,256] = raw[100000,256]_f32 @ W1c^T (bf16 out) ----
// 4 waves/block; block owns 128-col half; wave owns 32 cols. B staged to LDS
// once, then asm ds_read -> B[2][8] register-stationary. Steady state: per
// 16-row strip: 16 asm global_load_dwordx4 (stay in flight), cvt_pk, 16 MFMA,
// 8 asm stores; loop-bottom s_waitcnt vmcnt(8) (counted, never 0 - waits the
// 16 loads, not the store acks). mfma frags (m89/m91): A row=lane&15
// k=(lane>>4)*8+e; B col=lane&15; D col=lane&15 row=(lane>>4)*4+e.
__global__ __launch_bounds__(256)
void gemm_P(const float* __restrict__ raw, const short* __restrict__ W1c,
            short* __restrict__ P) {
  __shared__ char Blds[65536];
  const int tid  = threadIdx.x;
  const int wave = tid >> 6, lane = tid & 63;
  const int r16  = lane & 15, kg = lane >> 4;
  const int half = blockIdx.x & 1;
  const int res  = blockIdx.x >> 1;          // 0..255 strip residue
  const int col0 = half * 128 + wave * 32;
  const u32 swz  = (u32)(r16 & 7) << 4;

  // stage 64 KB half image (linear copy of pre-swizzled global image)
#pragma unroll
  for (int it = 0; it < 16; ++it)
    gload_lds16((const char*)W1c + half * 65536 + it * 4096 + tid * 16,
                Blds + it * 4096 + wave * 1024);
  __syncthreads();

  // B frags -> registers via asm ds_read (cannot be rematerialized)
  bf16x8 B[2][8];
#pragma unroll
  for (int n = 0; n < 2; ++n)
#pragma unroll
    for (int ks = 0; ks < 8; ++ks) {
      u32 a = (u32)(size_t)Blds
            + (u32)((ks >> 1) * 16384 + (wave * 32 + n * 16 + r16) * 128)
            + ((u32)((ks & 1) * 64 + kg * 16) ^ swz);
      DSR(B[n][ks], a);
    }
  WAITLGKM(); SBAR();

  int s = res;
  f32x4 af[16];
  {
    const float* x = raw + (size_t)(s * 16 + r16) * DIM + kg * 8;
    GL4(af[0],  x, 0);   GL4(af[1],  x, 16);
    GL4(af[2],  x, 128); GL4(af[3],  x, 144);
    GL4(af[4],  x, 256); GL4(af[5],  x, 272);
    GL4(af[6],  x, 384); GL4(af[7],  x, 400);
    GL4(af[8],  x, 512); GL4(af[9],  x, 528);
    GL4(af[10], x, 640); GL4(af[11], x, 656);
    GL4(af[12], x, 768); GL4(af[13], x, 784);
    GL4(af[14], x, 896); GL4(af[15], x, 912);
  }
  WAITVM(0); SBAR();

  for (; s < SNP; s += 256) {
    // convert current strip's A (ready per the preceding wait)
    bf16x8 ab[8];
#pragma unroll
    for (int ks = 0; ks < 8; ++ks) {
      f32x4 lo = af[2 * ks], hi = af[2 * ks + 1];
      u32 w0 = cvtpk(lo[0], lo[1]), w1 = cvtpk(lo[2], lo[3]);
      u32 w2 = cvtpk(hi[0], hi[1]), w3 = cvtpk(hi[2], hi[3]);
      __attribute__((ext_vector_type(4))) u32 t;
      t[0] = w0; t[1] = w1; t[2] = w2; t[3] = w3;
      ab[ks] = __builtin_bit_cast(bf16x8, t);
    }
    // issue next strip's loads (WAR on af orders them after the cvt reads)
    {
      int sn = s + 256; if (sn >= SNP) sn = s;
      const float* x = raw + (size_t)(sn * 16 + r16) * DIM + kg * 8;
      GL4(af[0],  x, 0);   GL4(af[1],  x, 16);
      GL4(af[2],  x, 128); GL4(af[3],  x, 144);
      GL4(af[4],  x, 256); GL4(af[5],  x, 272);
      GL4(af[6],  x, 384); GL4(af[7],  x, 400);
      GL4(af[8],  x, 512); GL4(af[9],  x, 528);
      GL4(af[10], x, 640); GL4(af[11], x, 656);
      GL4(af[12], x, 768); GL4(af[13], x, 784);
      GL4(af[14], x, 896); GL4(af[15], x, 912);
    }

    f32x4 acc0 = (f32x4){0.f, 0.f, 0.f, 0.f};
    f32x4 acc1 = (f32x4){0.f, 0.f, 0.f, 0.f};
#pragma unroll
    for (int ks = 0; ks < 8; ++ks) {
      acc0 = __builtin_amdgcn_mfma_f32_16x16x32_bf16(ab[ks], B[0][ks], acc0, 0, 0, 0);
      acc1 = __builtin_amdgcn_mfma_f32_16x16x32_bf16(ab[ks], B[1][ks], acc1, 0, 0, 0);
    }

    // 8 asm stores (exact vmcnt accounting)
    short* pb = P + (size_t)(s * 16 + kg * 4) * 256 + col0 + r16;
    {
      u32 v;
      v = (unsigned short)f2b(acc0[0]); GSH(pb, v, 0);
      v = (unsigned short)f2b(acc0[1]); GSH(pb, v, 512);
      v = (unsigned short)f2b(acc0[2]); GSH(pb, v, 1024);
      v = (unsigned short)f2b(acc0[3]); GSH(pb, v, 1536);
      v = (unsigned short)f2b(acc1[0]); GSH(pb, v, 32);
      v = (unsigned short)f2b(acc1[1]); GSH(pb, v, 544);
      v = (unsigned short)f2b(acc1[2]); GSH(pb, v, 1056);
      v = (unsigned short)f2b(acc1[3]); GSH(pb, v, 1568);
    }
    // counted wait: outstanding = [16 loads][8 stores] -> retires the loads only
    SBAR(); WAITVM(8); SBAR();
  }
}

// ---- Q[40960,256] = h1[40960,128]_bf16 @ W2c^T (bf16 out), same template ----
__global__ __launch_bounds__(256)
void gemm_Q(const short* __restrict__ h1, const short* __restrict__ W2c,
            short* __restrict__ Q) {
  __shared__ char Blds[32768];
  const int tid  = threadIdx.x;
  const int wave = tid >> 6, lane = tid & 63;
  const int r16  = lane & 15, kg = lane >> 4;
  const int half = blockIdx.x & 1;
  const int res  = blockIdx.x >> 1;
  const int col0 = half * 128 + wave * 32;
  const u32 swz  = (u32)(r16 & 7) << 4;

#pragma unroll
  for (int it = 0; it < 8; ++it)
    gload_lds16((const char*)W2c + half * 32768 + it * 4096 + tid * 16,
                Blds + it * 4096 + wave * 1024);
  __syncthreads();

  bf16x8 B[2][4];
#pragma unroll
  for (int n = 0; n < 2; ++n)
#pragma unroll
    for (int ks = 0; ks < 4; ++ks) {
      u32 a = (u32)(size_t)Blds
            + (u32)((ks >> 1) * 16384 + (wave * 32 + n * 16 + r16) * 128)
            + ((u32)((ks & 1) * 64 + kg * 16) ^ swz);
      DSR(B[n][ks], a);
    }
  WAITLGKM(); SBAR();

  int s = res;
  bf16x8 a[4];
  {
    const short* x = h1 + (size_t)(s * 16 + r16) * OUTD + kg * 8;
    GL4(a[0], x, 0); GL4(a[1], x, 64); GL4(a[2], x, 128); GL4(a[3], x, 192);
  }
  WAITVM(0); SBAR();

  for (; s < SNQ; s += 256) {
    f32x4 acc0 = (f32x4){0.f, 0.f, 0.f, 0.f};
    f32x4 acc1 = (f32x4){0.f, 0.f, 0.f, 0.f};
#pragma unroll
    for (int ks = 0; ks < 4; ++ks) {
      acc0 = __builtin_amdgcn_mfma_f32_16x16x32_bf16(a[ks], B[0][ks], acc0, 0, 0, 0);
      acc1 = __builtin_amdgcn_mfma_f32_16x16x32_bf16(a[ks], B[1][ks], acc1, 0, 0, 0);
    }
    // issue next strip's loads (after MFMAs consumed a[])
    {
      int sn = s + 256; if (sn >= SNQ) sn = s;
      const short* x = h1 + (size_t)(sn * 16 + r16) * OUTD + kg * 8;
      GL4(a[0], x, 0); GL4(a[1], x, 64); GL4(a[2], x, 128); GL4(a[3], x, 192);
    }

    short* qb = Q + (size_t)(s * 16 + kg * 4) * 256 + col0 + r16;
    {
      u32 v;
      v = (unsigned short)f2b(acc0[0]); GSH(qb, v, 0);
      v = (unsigned short)f2b(acc0[1]); GSH(qb, v, 512);
      v = (unsigned short)f2b(acc0[2]); GSH(qb, v, 1024);
      v = (unsigned short)f2b(acc0[3]); GSH(qb, v, 1536);
      v = (unsigned short)f2b(acc1[0]); GSH(qb, v, 32);
      v = (unsigned short)f2b(acc1[1]); GSH(qb, v, 544);
      v = (unsigned short)f2b(acc1[2]); GSH(qb, v, 1056);
      v = (unsigned short)f2b(acc1[3]); GSH(qb, v, 1568);
    }
    SBAR(); WAITVM(8); SBAR();   // retires the 4 loads, leaves store acks
  }
}

// ---- h1[i] = relu(P[nodes1[i]][0:128] + 0.1 * sum_k P[neighs1[i,k]][128:256]) ----
__global__ void gather1(const short* __restrict__ P, const int* __restrict__ nodes1,
                        const int* __restrict__ neighs1, short* __restrict__ h1) {
  int g = threadIdx.x >> 4, t = threadIdx.x & 15;
  int row = blockIdx.x * 16 + g;
  int sn = nodes1[row];
  bf16x8 sv = *(const bf16x8*)(P + (size_t)sn * 256 + t * 8);
  float acc[8];
#pragma unroll
  for (int e = 0; e < 8; ++e) acc[e] = 0.f;
#pragma unroll
  for (int k = 0; k < KN; ++k) {
    int nn = neighs1[row * KN + k];
    bf16x8 nv = *(const bf16x8*)(P + (size_t)nn * 256 + 128 + t * 8);
#pragma unroll
    for (int e = 0; e < 8; ++e) acc[e] += b2f(nv[e]);
  }
  bf16x8 o;
#pragma unroll
  for (int e = 0; e < 8; ++e) o[e] = f2b(fmaxf(b2f(sv[e]) + 0.1f * acc[e], 0.f));
  *(bf16x8*)(h1 + (size_t)row * OUTD + t * 8) = o;
}

// ---- out[i] = relu(Q[map2[i]][0:128] + 0.1 * sum_k Q[neighs2[i,k]][128:256]) f32 ----
__global__ void gather2(const short* __restrict__ Q, const int* __restrict__ map2,
                        const int* __restrict__ neighs2, float* __restrict__ out) {
  int g = threadIdx.x >> 4, t = threadIdx.x & 15;
  int row = blockIdx.x * 16 + g;
  int sn = map2[row];
  bf16x8 sv = *(const bf16x8*)(Q + (size_t)sn * 256 + t * 8);
  float acc[8];
#pragma unroll
  for (int e = 0; e < 8; ++e) acc[e] = 0.f;
#pragma unroll
  for (int k = 0; k < KN; ++k) {
    int nn = neighs2[row * KN + k];
    bf16x8 nv = *(const bf16x8*)(Q + (size_t)nn * 256 + 128 + t * 8);
#pragma unroll
    for (int e = 0; e < 8; ++e) acc[e] += b2f(nv[e]);
  }
  float* orow = out + (size_t)row * OUTD + t * 8;
  float4 o0, o1;
  o0.x = fmaxf(b2f(sv[0]) + 0.1f * acc[0], 0.f);
  o0.y = fmaxf(b2f(sv[1]) + 0.1f * acc[1], 0.f);
  o0.z = fmaxf(b2f(sv[2]) + 0.1f * acc[2], 0.f);
  o0.w = fmaxf(b2f(sv[3]) + 0.1f * acc[3], 0.f);
  o1.x = fmaxf(b2f(sv[4]) + 0.1f * acc[4], 0.f);
  o1.y = fmaxf(b2f(sv[5]) + 0.1f * acc[5], 0.f);
  o1.z = fmaxf(b2f(sv[6]) + 0.1f * acc[6], 0.f);
  o1.w = fmaxf(b2f(sv[7]) + 0.1f * acc[7], 0.f);
  *(float4*)orow = o0;
  *(float4*)(orow + 4) = o1;
}

extern "C" void kernel_launch(void* const* d_in, const int* in_sizes, int n_in,
                              void* d_out, int out_size, void* d_ws, size_t ws_size,
                              hipStream_t stream) {
  const float* raw     = (const float*)d_in[0];
  const float* W1      = (const float*)d_in[1];
  const float* W2      = (const float*)d_in[2];
  const int*   nodes1  = (const int*)d_in[3];
  const int*   neighs1 = (const int*)d_in[4];
  const int*   map2    = (const int*)d_in[5];
  const int*   neighs2 = (const int*)d_in[6];
  float* out = (float*)d_out;

  char* ws = (char*)d_ws;
  short* W1c = (short*)(ws);                 // 131,072 B (2 halves x 4 K-pages, swizzled)
  short* W2c = (short*)(ws + 131072);        //  65,536 B (2 halves x 2 K-pages, swizzled)
  short* P   = (short*)(ws + 196608);        // 100000*256*2 = 51,200,000 B
  short* Q   = (short*)(ws + 196608);        // alias (P dead after gather1)
  short* h1  = (short*)(ws + 51396608);      // 40960*128*2 = 10,485,760 B
                                             // total 61,882,368 B

  build_wc<<<256, 256, 0, stream>>>(W1, W2, W1c, W2c);
  gemm_P<<<512, 256, 0, stream>>>(raw, W1c, P);
  gather1<<<N1N / 16, 256, 0, stream>>>(P, nodes1, neighs1, h1);
  gemm_Q<<<512, 256, 0, stream>>>(h1, W2c, Q);
  gather2<<<BATCH / 16, 256, 0, stream>>>(Q, map2, neighs2, out);
}

// Round 11
// 112.891 us; speedup vs baseline: 1.4106x; 1.2626x over previous
//
#include <hip/hip_runtime.h>
#include <hip/hip_bf16.h>

#define N_RAW  100000
#define DIM    256
#define OUTD   128
#define KN     10
#define N1N    40960
#define BATCH  4096
#define SNP    6250   // 100000/16
#define SNQ    2560   // 40960/16

typedef __attribute__((ext_vector_type(8))) short bf16x8;
typedef __attribute__((ext_vector_type(4))) float f32x4;
typedef __attribute__((ext_vector_type(4))) unsigned int u32x4;
typedef unsigned int u32;

static __device__ inline float b2f(short s) {
  unsigned u = ((unsigned)(unsigned short)s) << 16;
  return __builtin_bit_cast(float, u);
}
static __device__ inline short f2b(float f) {
  unsigned u = __builtin_bit_cast(unsigned, f);
  unsigned r = (u + 0x7fff + ((u >> 16) & 1)) >> 16;  // RNE
  return (short)r;
}
static __device__ inline u32 cvtpk(float lo, float hi) {
  u32 r;
  asm("v_cvt_pk_bf16_f32 %0, %1, %2" : "=v"(r) : "v"(lo), "v"(hi));
  return r;
}
static __device__ inline void gload_lds16(const void* g, void* l) {
  __builtin_amdgcn_global_load_lds((const __attribute__((address_space(1))) u32*)g,
                                   (__attribute__((address_space(3))) u32*)l, 16, 0, 0);
}

// ---- combined weights, bf16, pre-swizzled QUARTER images ----
// Quarter qq = output-cols [qq*64,(qq+1)*64). Within quarter: k-pages of 64 k.
// W1c byte(j,k) = (j>>6)*32768 + (k>>6)*8192 + (j&63)*128 + ((2*(k&63)) ^ ((j&7)<<4))
// W2c byte(j,k) = (j>>6)*16384 + (k>>6)*8192 + (j&63)*128 + ((2*(k&63)) ^ ((j&7)<<4))
__global__ void build_wc(const float* __restrict__ W1, const float* __restrict__ W2,
                         short* __restrict__ W1c, short* __restrict__ W2c) {
  int i = blockIdx.x * blockDim.x + threadIdx.x;   // 65536 total
  {
    int j = i >> 8, k = i & 255;
    float v = (j < OUTD) ? W1[j * (2 * DIM) + k] : W1[(j - OUTD) * (2 * DIM) + DIM + k];
    u32 byte = (u32)((j >> 6) * 32768 + (k >> 6) * 8192 + (j & 63) * 128)
             + (((u32)(2 * (k & 63))) ^ ((u32)(j & 7) << 4));
    *(short*)((char*)W1c + byte) = f2b(v);
  }
  if (i < 256 * 128) {
    int j = i >> 7, k = i & 127;
    float v = (j < OUTD) ? W2[j * (2 * OUTD) + k] : W2[(j - OUTD) * (2 * OUTD) + OUTD + k];
    u32 byte = (u32)((j >> 6) * 16384 + (k >> 6) * 8192 + (j & 63) * 128)
             + (((u32)(2 * (k & 63))) ^ ((u32)(j & 7) << 4));
    *(short*)((char*)W2c + byte) = f2b(v);
  }
}

// ---- P[100000,256] = raw[100000,256]_f32 @ W1c^T (bf16 out) ----
// Occupancy-first (build_x1 recipe): 512 thr / 8 waves, wave = one 16-row
// strip x 64-col quarter. B quarter (32 KB) in LDS, staged once, ONE barrier.
// acc[4]=16 VGPR, phase loads single-buffered -> ~56 VGPR, launch_bounds
// (512,8) -> 8 waves/SIMD, 4 blocks/CU -> 32 waves/CU. Per-phase latency is
// hidden by wave TLP, not per-wave pipelining.
// mfma frags (m89/m91): A row=lane&15 k=(lane>>4)*8+e; B col=lane&15; D
// col=lane&15 row=(lane>>4)*4+e.
__global__ __launch_bounds__(512, 8)
void gemm_P(const float* __restrict__ raw, const short* __restrict__ W1c,
            short* __restrict__ P) {
  __shared__ char Blds[32768];
  const int tid  = threadIdx.x;
  const int wave = tid >> 6, lane = tid & 63;
  const int r16  = lane & 15, kg = lane >> 4;
  const int q    = blockIdx.x & 3;
  const int sg   = blockIdx.x >> 2;
  const u32 swz  = (u32)(r16 & 7) << 4;

  // stage 32 KB quarter image: 4 iters x (8 waves x 64 lanes x 16 B)
#pragma unroll
  for (int it = 0; it < 4; ++it)
    gload_lds16((const char*)W1c + q * 32768 + it * 8192 + wave * 1024 + lane * 16,
                Blds + it * 8192 + wave * 1024);
  __syncthreads();

  const int s = sg * 8 + wave;
  if (s >= SNP) return;

  const float* x = raw + (size_t)(s * 16 + r16) * DIM + kg * 8;

  f32x4 acc[4];
#pragma unroll
  for (int n = 0; n < 4; ++n) acc[n] = (f32x4){0.f, 0.f, 0.f, 0.f};

#pragma unroll
  for (int p = 0; p < 4; ++p) {
    // phase p covers k in [p*64, p*64+64) = ks {2p, 2p+1}
    f32x4 v0 = *(const f32x4*)(x + p * 64);
    f32x4 v1 = *(const f32x4*)(x + p * 64 + 4);
    f32x4 v2 = *(const f32x4*)(x + p * 64 + 32);
    f32x4 v3 = *(const f32x4*)(x + p * 64 + 36);

    u32x4 t0, t1;
    t0[0] = cvtpk(v0[0], v0[1]); t0[1] = cvtpk(v0[2], v0[3]);
    t0[2] = cvtpk(v1[0], v1[1]); t0[3] = cvtpk(v1[2], v1[3]);
    t1[0] = cvtpk(v2[0], v2[1]); t1[1] = cvtpk(v2[2], v2[3]);
    t1[2] = cvtpk(v3[0], v3[1]); t1[3] = cvtpk(v3[2], v3[3]);
    bf16x8 ab0 = __builtin_bit_cast(bf16x8, t0);   // ks = 2p
    bf16x8 ab1 = __builtin_bit_cast(bf16x8, t1);   // ks = 2p+1

#pragma unroll
    for (int n = 0; n < 4; ++n) {
      u32 base = (u32)(p * 8192 + (n * 16 + r16) * 128);
      bf16x8 b0 = *(const bf16x8*)(Blds + base + (((u32)(kg * 16)) ^ swz));
      bf16x8 b1 = *(const bf16x8*)(Blds + base + (((u32)(64 + kg * 16)) ^ swz));
      acc[n] = __builtin_amdgcn_mfma_f32_16x16x32_bf16(ab0, b0, acc[n], 0, 0, 0);
      acc[n] = __builtin_amdgcn_mfma_f32_16x16x32_bf16(ab1, b1, acc[n], 0, 0, 0);
    }
  }

  short* pb = P + (size_t)(s * 16 + kg * 4) * 256 + q * 64 + r16;
#pragma unroll
  for (int n = 0; n < 4; ++n)
#pragma unroll
    for (int j = 0; j < 4; ++j)
      pb[j * 256 + n * 16] = f2b(acc[n][j]);
}

// ---- Q[40960,256] = h1[40960,128]_bf16 @ W2c^T (bf16 out), same recipe ----
__global__ __launch_bounds__(512, 8)
void gemm_Q(const short* __restrict__ h1, const short* __restrict__ W2c,
            short* __restrict__ Q) {
  __shared__ char Blds[16384];
  const int tid  = threadIdx.x;
  const int wave = tid >> 6, lane = tid & 63;
  const int r16  = lane & 15, kg = lane >> 4;
  const int q    = blockIdx.x & 3;
  const int sg   = blockIdx.x >> 2;
  const u32 swz  = (u32)(r16 & 7) << 4;

#pragma unroll
  for (int it = 0; it < 2; ++it)
    gload_lds16((const char*)W2c + q * 16384 + it * 8192 + wave * 1024 + lane * 16,
                Blds + it * 8192 + wave * 1024);
  __syncthreads();

  const int s = sg * 8 + wave;
  if (s >= SNQ) return;

  const short* x = h1 + (size_t)(s * 16 + r16) * OUTD + kg * 8;
  bf16x8 a0 = *(const bf16x8*)(x);
  bf16x8 a1 = *(const bf16x8*)(x + 32);
  bf16x8 a2 = *(const bf16x8*)(x + 64);
  bf16x8 a3 = *(const bf16x8*)(x + 96);

  f32x4 acc[4];
#pragma unroll
  for (int n = 0; n < 4; ++n) acc[n] = (f32x4){0.f, 0.f, 0.f, 0.f};

#pragma unroll
  for (int n = 0; n < 4; ++n) {
    u32 row = (u32)((n * 16 + r16) * 128);
    bf16x8 b0 = *(const bf16x8*)(Blds + row + (((u32)(kg * 16)) ^ swz));
    bf16x8 b1 = *(const bf16x8*)(Blds + row + (((u32)(64 + kg * 16)) ^ swz));
    bf16x8 b2 = *(const bf16x8*)(Blds + 8192 + row + (((u32)(kg * 16)) ^ swz));
    bf16x8 b3 = *(const bf16x8*)(Blds + 8192 + row + (((u32)(64 + kg * 16)) ^ swz));
    acc[n] = __builtin_amdgcn_mfma_f32_16x16x32_bf16(a0, b0, acc[n], 0, 0, 0);
    acc[n] = __builtin_amdgcn_mfma_f32_16x16x32_bf16(a1, b1, acc[n], 0, 0, 0);
    acc[n] = __builtin_amdgcn_mfma_f32_16x16x32_bf16(a2, b2, acc[n], 0, 0, 0);
    acc[n] = __builtin_amdgcn_mfma_f32_16x16x32_bf16(a3, b3, acc[n], 0, 0, 0);
  }

  short* qb = Q + (size_t)(s * 16 + kg * 4) * 256 + q * 64 + r16;
#pragma unroll
  for (int n = 0; n < 4; ++n)
#pragma unroll
    for (int j = 0; j < 4; ++j)
      qb[j * 256 + n * 16] = f2b(acc[n][j]);
}

// ---- h1[i] = relu(P[nodes1[i]][0:128] + 0.1 * sum_k P[neighs1[i,k]][128:256]) ----
__global__ void gather1(const short* __restrict__ P, const int* __restrict__ nodes1,
                        const int* __restrict__ neighs1, short* __restrict__ h1) {
  int g = threadIdx.x >> 4, t = threadIdx.x & 15;
  int row = blockIdx.x * 16 + g;
  int sn = nodes1[row];
  bf16x8 sv = *(const bf16x8*)(P + (size_t)sn * 256 + t * 8);
  float acc[8];
#pragma unroll
  for (int e = 0; e < 8; ++e) acc[e] = 0.f;
#pragma unroll
  for (int k = 0; k < KN; ++k) {
    int nn = neighs1[row * KN + k];
    bf16x8 nv = *(const bf16x8*)(P + (size_t)nn * 256 + 128 + t * 8);
#pragma unroll
    for (int e = 0; e < 8; ++e) acc[e] += b2f(nv[e]);
  }
  bf16x8 o;
#pragma unroll
  for (int e = 0; e < 8; ++e) o[e] = f2b(fmaxf(b2f(sv[e]) + 0.1f * acc[e], 0.f));
  *(bf16x8*)(h1 + (size_t)row * OUTD + t * 8) = o;
}

// ---- out[i] = relu(Q[map2[i]][0:128] + 0.1 * sum_k Q[neighs2[i,k]][128:256]) f32 ----
__global__ void gather2(const short* __restrict__ Q, const int* __restrict__ map2,
                        const int* __restrict__ neighs2, float* __restrict__ out) {
  int g = threadIdx.x >> 4, t = threadIdx.x & 15;
  int row = blockIdx.x * 16 + g;
  int sn = map2[row];
  bf16x8 sv = *(const bf16x8*)(Q + (size_t)sn * 256 + t * 8);
  float acc[8];
#pragma unroll
  for (int e = 0; e < 8; ++e) acc[e] = 0.f;
#pragma unroll
  for (int k = 0; k < KN; ++k) {
    int nn = neighs2[row * KN + k];
    bf16x8 nv = *(const bf16x8*)(Q + (size_t)nn * 256 + 128 + t * 8);
#pragma unroll
    for (int e = 0; e < 8; ++e) acc[e] += b2f(nv[e]);
  }
  float* orow = out + (size_t)row * OUTD + t * 8;
  float4 o0, o1;
  o0.x = fmaxf(b2f(sv[0]) + 0.1f * acc[0], 0.f);
  o0.y = fmaxf(b2f(sv[1]) + 0.1f * acc[1], 0.f);
  o0.z = fmaxf(b2f(sv[2]) + 0.1f * acc[2], 0.f);
  o0.w = fmaxf(b2f(sv[3]) + 0.1f * acc[3], 0.f);
  o1.x = fmaxf(b2f(sv[4]) + 0.1f * acc[4], 0.f);
  o1.y = fmaxf(b2f(sv[5]) + 0.1f * acc[5], 0.f);
  o1.z = fmaxf(b2f(sv[6]) + 0.1f * acc[6], 0.f);
  o1.w = fmaxf(b2f(sv[7]) + 0.1f * acc[7], 0.f);
  *(float4*)orow = o0;
  *(float4*)(orow + 4) = o1;
}

extern "C" void kernel_launch(void* const* d_in, const int* in_sizes, int n_in,
                              void* d_out, int out_size, void* d_ws, size_t ws_size,
                              hipStream_t stream) {
  const float* raw     = (const float*)d_in[0];
  const float* W1      = (const float*)d_in[1];
  const float* W2      = (const float*)d_in[2];
  const int*   nodes1  = (const int*)d_in[3];
  const int*   neighs1 = (const int*)d_in[4];
  const int*   map2    = (const int*)d_in[5];
  const int*   neighs2 = (const int*)d_in[6];
  float* out = (float*)d_out;

  char* ws = (char*)d_ws;
  short* W1c = (short*)(ws);                 // 131,072 B (4 swizzled 32 KB quarters)
  short* W2c = (short*)(ws + 131072);        //  65,536 B (4 swizzled 16 KB quarters)
  short* P   = (short*)(ws + 196608);        // 100000*256*2 = 51,200,000 B
  short* Q   = (short*)(ws + 196608);        // alias (P dead after gather1)
  short* h1  = (short*)(ws + 51396608);      // 40960*128*2 = 10,485,760 B
                                             // total 61,882,368 B

  build_wc<<<256, 256, 0, stream>>>(W1, W2, W1c, W2c);
  gemm_P<<<3128, 512, 0, stream>>>(raw, W1c, P);   // 782 sgroups x 4 quarters
  gather1<<<N1N / 16, 256, 0, stream>>>(P, nodes1, neighs1, h1);
  gemm_Q<<<1280, 512, 0, stream>>>(h1, W2c, Q);    // 320 sgroups x 4 quarters
  gather2<<<BATCH / 16, 256, 0, stream>>>(Q, map2, neighs2, out);
}

// Round 12
// 104.271 us; speedup vs baseline: 1.5272x; 1.0827x over previous
//
#include <hip/hip_runtime.h>
#include <hip/hip_bf16.h>

#define N_RAW  100000
#define DIM    256
#define OUTD   128
#define KN     10
#define N1N    40960
#define BATCH  4096
#define SNP    6250   // 100000/16
#define SNQ    2560   // 40960/16

typedef __attribute__((ext_vector_type(8))) short bf16x8;
typedef __attribute__((ext_vector_type(4))) float f32x4;
typedef __attribute__((ext_vector_type(4))) unsigned int u32x4;
typedef unsigned int u32;

static __device__ inline float b2f(short s) {
  unsigned u = ((unsigned)(unsigned short)s) << 16;
  return __builtin_bit_cast(float, u);
}
static __device__ inline short f2b(float f) {
  unsigned u = __builtin_bit_cast(unsigned, f);
  unsigned r = (u + 0x7fff + ((u >> 16) & 1)) >> 16;  // RNE
  return (short)r;
}
static __device__ inline u32 cvtpk(float lo, float hi) {
  u32 r;
  asm("v_cvt_pk_bf16_f32 %0, %1, %2" : "=v"(r) : "v"(lo), "v"(hi));
  return r;
}
static __device__ inline void gload_lds16(const void* g, void* l) {
  __builtin_amdgcn_global_load_lds((const __attribute__((address_space(1))) u32*)g,
                                   (__attribute__((address_space(3))) u32*)l, 16, 0, 0);
}

// ---- combined weights, bf16, pre-swizzled QUARTER images (unchanged from r11) ----
// Quarter qq = output-cols [qq*64,(qq+1)*64). Within quarter: k-pages of 64 k.
// W1c byte(j,k) = (j>>6)*32768 + (k>>6)*8192 + (j&63)*128 + ((2*(k&63)) ^ ((j&7)<<4))
// W2c byte(j,k) = (j>>6)*16384 + (k>>6)*8192 + (j&63)*128 + ((2*(k&63)) ^ ((j&7)<<4))
__global__ void build_wc(const float* __restrict__ W1, const float* __restrict__ W2,
                         short* __restrict__ W1c, short* __restrict__ W2c) {
  int i = blockIdx.x * blockDim.x + threadIdx.x;   // 65536 total
  {
    int j = i >> 8, k = i & 255;
    float v = (j < OUTD) ? W1[j * (2 * DIM) + k] : W1[(j - OUTD) * (2 * DIM) + DIM + k];
    u32 byte = (u32)((j >> 6) * 32768 + (k >> 6) * 8192 + (j & 63) * 128)
             + (((u32)(2 * (k & 63))) ^ ((u32)(j & 7) << 4));
    *(short*)((char*)W1c + byte) = f2b(v);
  }
  if (i < 256 * 128) {
    int j = i >> 7, k = i & 127;
    float v = (j < OUTD) ? W2[j * (2 * OUTD) + k] : W2[(j - OUTD) * (2 * OUTD) + OUTD + k];
    u32 byte = (u32)((j >> 6) * 16384 + (k >> 6) * 8192 + (j & 63) * 128)
             + (((u32)(2 * (k & 63))) ^ ((u32)(j & 7) << 4));
    *(short*)((char*)W2c + byte) = f2b(v);
  }
}

// ---- P[100000,256] = raw[100000,256]_f32 @ W1c^T (bf16 out) ----
// 1024 thr / 16 waves; block = 8 strips x 128-col half (quarters 2h, 2h+1 of
// W1c = 64 KB LDS, staged once, ONE barrier). Wave (ws=w>>1, lq=w&1) = 16
// rows x 64 cols, acc[4]=16 VGPR. The 2 waves sharing a strip are same-CU ->
// A re-read hits L1/L2; the 2 col-halves' A re-read is L3-absorbed (r7:
// FETCH 106 MB with this exact bid&1 split). 2 blocks/CU -> 32 waves/CU.
// mfma frags (m89/m91): A row=lane&15 k=(lane>>4)*8+e; B col=lane&15; D
// col=lane&15 row=(lane>>4)*4+e.
__global__ __launch_bounds__(1024, 8)
void gemm_P(const float* __restrict__ raw, const short* __restrict__ W1c,
            short* __restrict__ P) {
  __shared__ char Blds[65536];
  const int tid  = threadIdx.x;
  const int wave = tid >> 6, lane = tid & 63;
  const int r16  = lane & 15, kg = lane >> 4;
  const int half = blockIdx.x & 1;
  const int sg   = blockIdx.x >> 1;
  const int lq   = wave & 1;           // local quarter within half
  const int wsn  = wave >> 1;          // strip within group, 0..7
  const u32 swz  = (u32)(r16 & 7) << 4;

  // stage 64 KB half image: 4 iters x (16 waves x 64 lanes x 16 B)
#pragma unroll
  for (int it = 0; it < 4; ++it)
    gload_lds16((const char*)W1c + half * 65536 + it * 16384 + wave * 1024 + lane * 16,
                Blds + it * 16384 + wave * 1024);
  __syncthreads();

  const int s = sg * 8 + wsn;
  if (s >= SNP) return;

  const float* x = raw + (size_t)(s * 16 + r16) * DIM + kg * 8;

  f32x4 acc[4];
#pragma unroll
  for (int n = 0; n < 4; ++n) acc[n] = (f32x4){0.f, 0.f, 0.f, 0.f};

#pragma unroll
  for (int p = 0; p < 4; ++p) {
    // phase p covers k in [p*64, p*64+64) = ks {2p, 2p+1}
    f32x4 v0 = *(const f32x4*)(x + p * 64);
    f32x4 v1 = *(const f32x4*)(x + p * 64 + 4);
    f32x4 v2 = *(const f32x4*)(x + p * 64 + 32);
    f32x4 v3 = *(const f32x4*)(x + p * 64 + 36);

    u32x4 t0, t1;
    t0[0] = cvtpk(v0[0], v0[1]); t0[1] = cvtpk(v0[2], v0[3]);
    t0[2] = cvtpk(v1[0], v1[1]); t0[3] = cvtpk(v1[2], v1[3]);
    t1[0] = cvtpk(v2[0], v2[1]); t1[1] = cvtpk(v2[2], v2[3]);
    t1[2] = cvtpk(v3[0], v3[1]); t1[3] = cvtpk(v3[2], v3[3]);
    bf16x8 ab0 = __builtin_bit_cast(bf16x8, t0);   // ks = 2p
    bf16x8 ab1 = __builtin_bit_cast(bf16x8, t1);   // ks = 2p+1

#pragma unroll
    for (int n = 0; n < 4; ++n) {
      u32 base = (u32)(lq * 32768 + p * 8192 + (n * 16 + r16) * 128);
      bf16x8 b0 = *(const bf16x8*)(Blds + base + (((u32)(kg * 16)) ^ swz));
      bf16x8 b1 = *(const bf16x8*)(Blds + base + (((u32)(64 + kg * 16)) ^ swz));
      acc[n] = __builtin_amdgcn_mfma_f32_16x16x32_bf16(ab0, b0, acc[n], 0, 0, 0);
      acc[n] = __builtin_amdgcn_mfma_f32_16x16x32_bf16(ab1, b1, acc[n], 0, 0, 0);
    }
  }

  short* pb = P + (size_t)(s * 16 + kg * 4) * 256 + half * 128 + lq * 64 + r16;
#pragma unroll
  for (int n = 0; n < 4; ++n)
#pragma unroll
    for (int j = 0; j < 4; ++j)
      pb[j * 256 + n * 16] = f2b(acc[n][j]);
}

// ---- Q[40960,256] = h1[40960,128]_bf16 @ W2c^T (bf16 out), same recipe ----
__global__ __launch_bounds__(1024, 8)
void gemm_Q(const short* __restrict__ h1, const short* __restrict__ W2c,
            short* __restrict__ Q) {
  __shared__ char Blds[32768];
  const int tid  = threadIdx.x;
  const int wave = tid >> 6, lane = tid & 63;
  const int r16  = lane & 15, kg = lane >> 4;
  const int half = blockIdx.x & 1;
  const int sg   = blockIdx.x >> 1;
  const int lq   = wave & 1;
  const int wsn  = wave >> 1;
  const u32 swz  = (u32)(r16 & 7) << 4;

  // stage 32 KB half image: 2 iters x 16 KB
#pragma unroll
  for (int it = 0; it < 2; ++it)
    gload_lds16((const char*)W2c + half * 32768 + it * 16384 + wave * 1024 + lane * 16,
                Blds + it * 16384 + wave * 1024);
  __syncthreads();

  const int s = sg * 8 + wsn;          // 320*8 = 2560 = SNQ exactly

  const short* x = h1 + (size_t)(s * 16 + r16) * OUTD + kg * 8;
  bf16x8 a0 = *(const bf16x8*)(x);
  bf16x8 a1 = *(const bf16x8*)(x + 32);
  bf16x8 a2 = *(const bf16x8*)(x + 64);
  bf16x8 a3 = *(const bf16x8*)(x + 96);

  f32x4 acc[4];
#pragma unroll
  for (int n = 0; n < 4; ++n) acc[n] = (f32x4){0.f, 0.f, 0.f, 0.f};

#pragma unroll
  for (int n = 0; n < 4; ++n) {
    u32 base = (u32)(lq * 16384 + (n * 16 + r16) * 128);
    bf16x8 b0 = *(const bf16x8*)(Blds + base + (((u32)(kg * 16)) ^ swz));
    bf16x8 b1 = *(const bf16x8*)(Blds + base + (((u32)(64 + kg * 16)) ^ swz));
    bf16x8 b2 = *(const bf16x8*)(Blds + base + 8192 + (((u32)(kg * 16)) ^ swz));
    bf16x8 b3 = *(const bf16x8*)(Blds + base + 8192 + (((u32)(64 + kg * 16)) ^ swz));
    acc[n] = __builtin_amdgcn_mfma_f32_16x16x32_bf16(a0, b0, acc[n], 0, 0, 0);
    acc[n] = __builtin_amdgcn_mfma_f32_16x16x32_bf16(a1, b1, acc[n], 0, 0, 0);
    acc[n] = __builtin_amdgcn_mfma_f32_16x16x32_bf16(a2, b2, acc[n], 0, 0, 0);
    acc[n] = __builtin_amdgcn_mfma_f32_16x16x32_bf16(a3, b3, acc[n], 0, 0, 0);
  }

  short* qb = Q + (size_t)(s * 16 + kg * 4) * 256 + half * 128 + lq * 64 + r16;
#pragma unroll
  for (int n = 0; n < 4; ++n)
#pragma unroll
    for (int j = 0; j < 4; ++j)
      qb[j * 256 + n * 16] = f2b(acc[n][j]);
}

// ---- h1[i] = relu(P[nodes1[i]][0:128] + 0.1 * sum_k P[neighs1[i,k]][128:256]) ----
__global__ void gather1(const short* __restrict__ P, const int* __restrict__ nodes1,
                        const int* __restrict__ neighs1, short* __restrict__ h1) {
  int g = threadIdx.x >> 4, t = threadIdx.x & 15;
  int row = blockIdx.x * 16 + g;
  int sn = nodes1[row];
  bf16x8 sv = *(const bf16x8*)(P + (size_t)sn * 256 + t * 8);
  float acc[8];
#pragma unroll
  for (int e = 0; e < 8; ++e) acc[e] = 0.f;
#pragma unroll
  for (int k = 0; k < KN; ++k) {
    int nn = neighs1[row * KN + k];
    bf16x8 nv = *(const bf16x8*)(P + (size_t)nn * 256 + 128 + t * 8);
#pragma unroll
    for (int e = 0; e < 8; ++e) acc[e] += b2f(nv[e]);
  }
  bf16x8 o;
#pragma unroll
  for (int e = 0; e < 8; ++e) o[e] = f2b(fmaxf(b2f(sv[e]) + 0.1f * acc[e], 0.f));
  *(bf16x8*)(h1 + (size_t)row * OUTD + t * 8) = o;
}

// ---- out[i] = relu(Q[map2[i]][0:128] + 0.1 * sum_k Q[neighs2[i,k]][128:256]) f32 ----
__global__ void gather2(const short* __restrict__ Q, const int* __restrict__ map2,
                        const int* __restrict__ neighs2, float* __restrict__ out) {
  int g = threadIdx.x >> 4, t = threadIdx.x & 15;
  int row = blockIdx.x * 16 + g;
  int sn = map2[row];
  bf16x8 sv = *(const bf16x8*)(Q + (size_t)sn * 256 + t * 8);
  float acc[8];
#pragma unroll
  for (int e = 0; e < 8; ++e) acc[e] = 0.f;
#pragma unroll
  for (int k = 0; k < KN; ++k) {
    int nn = neighs2[row * KN + k];
    bf16x8 nv = *(const bf16x8*)(Q + (size_t)nn * 256 + 128 + t * 8);
#pragma unroll
    for (int e = 0; e < 8; ++e) acc[e] += b2f(nv[e]);
  }
  float* orow = out + (size_t)row * OUTD + t * 8;
  float4 o0, o1;
  o0.x = fmaxf(b2f(sv[0]) + 0.1f * acc[0], 0.f);
  o0.y = fmaxf(b2f(sv[1]) + 0.1f * acc[1], 0.f);
  o0.z = fmaxf(b2f(sv[2]) + 0.1f * acc[2], 0.f);
  o0.w = fmaxf(b2f(sv[3]) + 0.1f * acc[3], 0.f);
  o1.x = fmaxf(b2f(sv[4]) + 0.1f * acc[4], 0.f);
  o1.y = fmaxf(b2f(sv[5]) + 0.1f * acc[5], 0.f);
  o1.z = fmaxf(b2f(sv[6]) + 0.1f * acc[6], 0.f);
  o1.w = fmaxf(b2f(sv[7]) + 0.1f * acc[7], 0.f);
  *(float4*)orow = o0;
  *(float4*)(orow + 4) = o1;
}

extern "C" void kernel_launch(void* const* d_in, const int* in_sizes, int n_in,
                              void* d_out, int out_size, void* d_ws, size_t ws_size,
                              hipStream_t stream) {
  const float* raw     = (const float*)d_in[0];
  const float* W1      = (const float*)d_in[1];
  const float* W2      = (const float*)d_in[2];
  const int*   nodes1  = (const int*)d_in[3];
  const int*   neighs1 = (const int*)d_in[4];
  const int*   map2    = (const int*)d_in[5];
  const int*   neighs2 = (const int*)d_in[6];
  float* out = (float*)d_out;

  char* ws = (char*)d_ws;
  short* W1c = (short*)(ws);                 // 131,072 B (4 swizzled 32 KB quarters)
  short* W2c = (short*)(ws + 131072);        //  65,536 B (4 swizzled 16 KB quarters)
  short* P   = (short*)(ws + 196608);        // 100000*256*2 = 51,200,000 B
  short* Q   = (short*)(ws + 196608);        // alias (P dead after gather1)
  short* h1  = (short*)(ws + 51396608);      // 40960*128*2 = 10,485,760 B
                                             // total 61,882,368 B

  build_wc<<<256, 256, 0, stream>>>(W1, W2, W1c, W2c);
  gemm_P<<<1564, 1024, 0, stream>>>(raw, W1c, P);  // 782 sgroups x 2 halves
  gather1<<<N1N / 16, 256, 0, stream>>>(P, nodes1, neighs1, h1);
  gemm_Q<<<640, 1024, 0, stream>>>(h1, W2c, Q);    // 320 sgroups x 2 halves
  gather2<<<BATCH / 16, 256, 0, stream>>>(Q, map2, neighs2, out);
}